// Round 11
// baseline (333.676 us; speedup 1.0000x reference)
//
#include <hip/hip_runtime.h>
#include <hip/hip_fp16.h>

#define N_NODES 50000
#define N_EDGES 600000
#define N_GRAPHS 64
#define IN_D 5
#define HID 128
#define EMB 64

#define CHUNK 512
#define NCHUNK ((N_NODES + CHUNK - 1) / CHUNK)   // 98
#define NREP 16          // psum replication factor (contention spread)
#define NLOC 4           // per-block local graph slots (64 sorted nodes span <=2-3)
#define RSTRIDE_H 136    // LDS row stride in halves (272 B, breaks pow2 banks)

typedef _Float16 half8 __attribute__((ext_vector_type(8)));
typedef _Float16 half2v __attribute__((ext_vector_type(2)));
typedef float float4v __attribute__((ext_vector_type(4)));

// ---------- 1. degree count (edge atomics; 50k addresses = low contention) ----------

__global__ __launch_bounds__(256) void k_count(
        const int* __restrict__ dst, int* __restrict__ cnt) {
    int e = blockIdx.x * blockDim.x + threadIdx.x;
    if (e < N_EDGES) atomicAdd(&cnt[dst[e]], 1);
}

// ---------- 2. merged CSR scan + dinv + all remaining init ----------
// Each block self-computes its chunk prefix by reducing cnt[0..base) directly
// (~10 MB total reads, ~2 us) — kills the chunksum dispatch. Also absorbs
// fill/psum zeroing and the W2/W3 fp16 transpose (must precede their consumers).

__global__ __launch_bounds__(256) void k_scan2(
        const int* __restrict__ cnt, int* __restrict__ row_start,
        float* __restrict__ dinv, int* __restrict__ fill,
        float* __restrict__ psum_rep,
        const float* __restrict__ W2, const float* __restrict__ W3,
        _Float16* __restrict__ Wt2, _Float16* __restrict__ Wt3) {
    __shared__ int sh[256];
    __shared__ int ws[4];
    int b = blockIdx.x, t = threadIdx.x;
    int lane = t & 63, w = t >> 6;
    int base = b * CHUNK;

    // chunk prefix: block-reduce cnt[0..base)
    int part = 0;
    for (int j = t; j < base; j += 256) part += cnt[j];
    sh[t] = part; __syncthreads();
    for (int off = 128; off > 0; off >>= 1) {
        if (t < off) sh[t] += sh[t + off];
        __syncthreads();
    }
    int pre = sh[0];

    // local exclusive scan (2 elems/thread)
    int i0 = base + 2 * t, i1 = i0 + 1;
    int c0 = (i0 < N_NODES) ? cnt[i0] : 0;
    int c1 = (i1 < N_NODES) ? cnt[i1] : 0;
    int v = c0 + c1;
    int s = v;
    #pragma unroll
    for (int off = 1; off < 64; off <<= 1) {
        int u = __shfl_up(s, off);
        if (lane >= off) s += u;
    }
    if (lane == 63) ws[w] = s;
    __syncthreads();
    if (t == 0) {
        int r = 0;
        #pragma unroll
        for (int j = 0; j < 4; ++j) { int xx = ws[j]; ws[j] = r; r += xx; }
    }
    __syncthreads();
    int excl = s - v + ws[w] + pre;
    if (i0 < N_NODES) { row_start[i0] = excl;      dinv[i0] = rsqrtf((float)c0 + 1.0f); }
    if (i1 < N_NODES) { row_start[i1] = excl + c0; dinv[i1] = rsqrtf((float)c1 + 1.0f); }
    if (b == 0 && t == 0) row_start[N_NODES] = N_EDGES;

    // absorbed init work (grid-stride over the 98*256 threads)
    int gt = b * 256 + t;
    const int NT = NCHUNK * 256;
    for (int i = gt; i < N_NODES; i += NT) fill[i] = 0;
    for (int i = gt; i < NREP * N_GRAPHS * HID; i += NT) psum_rep[i] = 0.f;
    for (int i = gt; i < 2 * HID * HID; i += NT) {
        int rem = i & (HID * HID - 1);
        int k = rem & 127, f = rem >> 7;
        if (i < HID * HID) Wt2[rem] = (_Float16)W2[k * HID + f];
        else               Wt3[rem] = (_Float16)W3[k * HID + f];
    }
}

// ---------- 3. scatter edges into CSR order ----------

__global__ __launch_bounds__(256) void k_scatter(
        const int* __restrict__ src, const int* __restrict__ dst,
        const float* __restrict__ dinv, const int* __restrict__ row_start,
        int* __restrict__ fill, int2* __restrict__ e_pack) {
    int e = blockIdx.x * blockDim.x + threadIdx.x;
    if (e >= N_EDGES) return;
    int d = dst[e];
    int pos = row_start[d] + atomicAdd(&fill[d], 1);
    int s = src[e];
    e_pack[pos] = make_int2(s, __float_as_int(dinv[s]));
}

// ---------- 4. fused layer 1: agg(x) + gemm1 + bn + relu -> H16 ----------

__global__ __launch_bounds__(256) void k_agg5g1(
        const float* __restrict__ x, const float* __restrict__ dinv,
        const int* __restrict__ row_start, const int2* __restrict__ e_pack,
        const float* __restrict__ W1, const float* __restrict__ b1,
        const float* __restrict__ g1, const float* __restrict__ be1,
        __half2* __restrict__ H16) {
    int gid = blockIdx.x * blockDim.x + threadIdx.x;
    int i = gid >> 3, k = gid & 7;
    if (i >= N_NODES) return;
    float acc = 0.f;
    if (k < IN_D) {
        int beg = row_start[i], end = row_start[i + 1];
        int e = beg;
        for (; e + 3 < end; e += 4) {
            int2 p0 = e_pack[e];
            int2 p1 = e_pack[e + 1];
            int2 p2 = e_pack[e + 2];
            int2 p3 = e_pack[e + 3];
            float x0 = x[p0.x * IN_D + k];
            float x1 = x[p1.x * IN_D + k];
            float x2 = x[p2.x * IN_D + k];
            float x3 = x[p3.x * IN_D + k];
            acc = fmaf(__int_as_float(p0.y), x0, acc);
            acc = fmaf(__int_as_float(p1.y), x1, acc);
            acc = fmaf(__int_as_float(p2.y), x2, acc);
            acc = fmaf(__int_as_float(p3.y), x3, acc);
        }
        for (; e < end; ++e) {
            int2 p = e_pack[e];
            acc = fmaf(__int_as_float(p.y), x[p.x * IN_D + k], acc);
        }
        float di = dinv[i];
        acc = di * (acc + di * x[i * IN_D + k]);
    }
    int lane = threadIdx.x & 63;
    int base = lane & ~7;
    float a0 = __shfl(acc, base + 0);
    float a1 = __shfl(acc, base + 1);
    float a2 = __shfl(acc, base + 2);
    float a3 = __shfl(acc, base + 3);
    float a4 = __shfl(acc, base + 4);
    const float rs = rsqrtf(1.0f + 1e-5f);
    int f0 = k * 16;
    #pragma unroll
    for (int u = 0; u < 8; ++u) {
        int fa = f0 + u * 2, fb = fa + 1;
        float va = b1[fa], vb = b1[fb];
        va = fmaf(a0, W1[0 * HID + fa], va); vb = fmaf(a0, W1[0 * HID + fb], vb);
        va = fmaf(a1, W1[1 * HID + fa], va); vb = fmaf(a1, W1[1 * HID + fb], vb);
        va = fmaf(a2, W1[2 * HID + fa], va); vb = fmaf(a2, W1[2 * HID + fb], vb);
        va = fmaf(a3, W1[3 * HID + fa], va); vb = fmaf(a3, W1[3 * HID + fb], vb);
        va = fmaf(a4, W1[4 * HID + fa], va); vb = fmaf(a4, W1[4 * HID + fb], vb);
        va = fmaf(va, g1[fa] * rs, be1[fa]);
        vb = fmaf(vb, g1[fb] * rs, be1[fb]);
        va = va > 0.f ? va : 0.f;
        vb = vb > 0.f ? vb : 0.f;
        H16[(size_t)i * 64 + k * 8 + u] = __floats2half2_rn(va, vb);
    }
}

// ---------- 5/6. fused layer: gather(Hsrc) -> LDS -> MFMA gemm -> out ----------
// Block = 64 nodes, 4 waves; wave w gathers its own 16 nodes into a wave-private
// LDS tile (row stride 272 B), then reads its MFMA A-fragments from LDS.
// No inter-wave dependency -> no barrier between gather and MFMA.
// POOL: fuse mean-pool epilogue (LDS accumulation + replicated global atomics).

template <bool POOL>
__global__ __launch_bounds__(256) void k_fuse(
        const __half2* __restrict__ Hsrc, const float* __restrict__ dinv,
        const int* __restrict__ row_start, const int2* __restrict__ e_pack,
        const _Float16* __restrict__ Wt, const float* __restrict__ bb,
        const float* __restrict__ gg, const float* __restrict__ bee,
        _Float16* __restrict__ Hdst,
        const int* __restrict__ batch, float* __restrict__ psum_rep) {
    __shared__ _Float16 shA[4 * 16 * RSTRIDE_H];   // 17408 B
    __shared__ float sh_pool[NLOC][HID];           // used only if POOL
    int t = threadIdx.x;
    int w = t >> 6, lane = t & 63;
    int blk = (int)blockIdx.x;
    const float rs = rsqrtf(1.0f + 1e-5f);

    int g0 = 0;
    if (POOL) {
        for (int i = t; i < NLOC * HID; i += 256) ((float*)sh_pool)[i] = 0.f;
        int nb0 = blk * 64;
        if (nb0 > N_NODES - 1) nb0 = N_NODES - 1;
        g0 = batch[nb0];
        __syncthreads();
    }

    // --- gather phase: 16 nodes per wave, wave-wide over 128 feats ---
    _Float16* myA = shA + w * 16 * RSTRIDE_H;
    for (int r = 0; r < 16; ++r) {
        int n = blk * 64 + w * 16 + r;
        float2 acc = make_float2(0.f, 0.f);
        if (n < N_NODES) {
            int beg = row_start[n], end = row_start[n + 1];
            int e = beg;
            for (; e + 7 < end; e += 8) {
                int2 p[8];
                float2 h[8];
                #pragma unroll
                for (int u = 0; u < 8; ++u) p[u] = e_pack[e + u];
                #pragma unroll
                for (int u = 0; u < 8; ++u)
                    h[u] = __half22float2(Hsrc[(size_t)p[u].x * 64 + lane]);
                #pragma unroll
                for (int u = 0; u < 8; ++u) {
                    float wt = __int_as_float(p[u].y);
                    acc.x = fmaf(wt, h[u].x, acc.x);
                    acc.y = fmaf(wt, h[u].y, acc.y);
                }
            }
            for (; e + 3 < end; e += 4) {
                int2 p[4];
                float2 h[4];
                #pragma unroll
                for (int u = 0; u < 4; ++u) p[u] = e_pack[e + u];
                #pragma unroll
                for (int u = 0; u < 4; ++u)
                    h[u] = __half22float2(Hsrc[(size_t)p[u].x * 64 + lane]);
                #pragma unroll
                for (int u = 0; u < 4; ++u) {
                    float wt = __int_as_float(p[u].y);
                    acc.x = fmaf(wt, h[u].x, acc.x);
                    acc.y = fmaf(wt, h[u].y, acc.y);
                }
            }
            for (; e < end; ++e) {
                int2 pe = e_pack[e];
                float wt = __int_as_float(pe.y);
                float2 f = __half22float2(Hsrc[(size_t)pe.x * 64 + lane]);
                acc.x = fmaf(wt, f.x, acc.x);
                acc.y = fmaf(wt, f.y, acc.y);
            }
            float di = dinv[n];
            float2 hs = __half22float2(Hsrc[(size_t)n * 64 + lane]);
            acc.x = di * fmaf(di, hs.x, acc.x);
            acc.y = di * fmaf(di, hs.y, acc.y);
        }
        half2v hv = { (_Float16)acc.x, (_Float16)acc.y };
        *(half2v*)(myA + r * RSTRIDE_H + lane * 2) = hv;
    }

    // --- MFMA phase (wave-private LDS, no barrier) ---
    int quad = lane >> 4, r16 = lane & 15;
    int nb = blk * 64 + w * 16;
    const _Float16* rowp = myA + r16 * RSTRIDE_H;
    half8 a[4];
    #pragma unroll
    for (int kb = 0; kb < 4; ++kb)
        a[kb] = *(const half8*)(rowp + kb * 32 + quad * 8);

    int gi4[4];
    if (POOL) {
        #pragma unroll
        for (int rr = 0; rr < 4; ++rr) {
            int n = nb + quad * 4 + rr;
            gi4[rr] = (n < N_NODES) ? batch[n] : -1;
        }
    }
    float* rep = POOL ? (psum_rep + (size_t)(blk & (NREP - 1)) * N_GRAPHS * HID) : nullptr;

    #pragma unroll
    for (int ft = 0; ft < 8; ++ft) {
        int f = ft * 16 + r16;
        const half8* Brow = (const half8*)(Wt + (size_t)f * 128);
        float4v acc = {0.f, 0.f, 0.f, 0.f};
        #pragma unroll
        for (int kb = 0; kb < 4; ++kb)
            acc = __builtin_amdgcn_mfma_f32_16x16x32_f16(a[kb], Brow[kb * 4 + quad],
                                                         acc, 0, 0, 0);
        float b0 = bb[f], g0f = gg[f] * rs, e0 = bee[f];
        if (POOL) {
            float partial = 0.f;
            int cur = -1;
            #pragma unroll
            for (int rr = 0; rr < 4; ++rr) {
                int gi = gi4[rr];
                if (gi >= 0) {
                    float v = fmaf(acc[rr] + b0, g0f, e0);
                    v = v > 0.f ? v : 0.f;
                    if (gi != cur) {
                        if (cur >= 0) {
                            int idx = cur - g0;
                            if (idx < NLOC) atomicAdd(&sh_pool[idx][f], partial);
                            else            atomicAdd(&rep[cur * HID + f], partial);
                        }
                        partial = 0.f; cur = gi;
                    }
                    partial += v;
                }
            }
            if (cur >= 0) {
                int idx = cur - g0;
                if (idx < NLOC) atomicAdd(&sh_pool[idx][f], partial);
                else            atomicAdd(&rep[cur * HID + f], partial);
            }
        } else {
            #pragma unroll
            for (int rr = 0; rr < 4; ++rr) {
                int n = nb + quad * 4 + rr;
                if (n < N_NODES) {
                    float v = fmaf(acc[rr] + b0, g0f, e0);
                    v = v > 0.f ? v : 0.f;
                    Hdst[(size_t)n * 128 + f] = (_Float16)v;
                }
            }
        }
    }

    if (POOL) {
        __syncthreads();
        for (int i = t; i < NLOC * HID; i += 256) {
            int idx = i >> 7, f = i & 127;
            float v = sh_pool[idx][f];
            int g = g0 + idx;
            if (v != 0.f && g < N_GRAPHS) atomicAdd(&rep[g * HID + f], v);
        }
    }
}

// ---------- 7. projection (+ graph counts via binary search, no atomics) ----------

__device__ __forceinline__ int lower_bound_batch(const int* __restrict__ batch, int val) {
    int lo = 0, hi = N_NODES;
    while (lo < hi) {
        int mid = (lo + hi) >> 1;
        if (batch[mid] < val) lo = mid + 1;
        else hi = mid;
    }
    return lo;
}

__global__ void k_final(const float* __restrict__ psum_rep, const int* __restrict__ batch,
                        const float* __restrict__ Wp, const float* __restrict__ bp,
                        float* __restrict__ out) {
    __shared__ float s_p[HID];
    int gi = blockIdx.x, e = threadIdx.x;   // 64 threads
    for (int f = e; f < HID; f += EMB) {
        float v = 0.f;
        #pragma unroll
        for (int r = 0; r < NREP; ++r)
            v += psum_rep[(size_t)r * N_GRAPHS * HID + gi * HID + f];
        s_p[f] = v;
    }
    int lane = e & 63;
    int r = 0;
    if (lane < 2) r = lower_bound_batch(batch, gi + lane);
    int c0 = __shfl(r, 0), c1 = __shfl(r, 1);
    float inv = 1.0f / fmaxf((float)(c1 - c0), 1.0f);
    __syncthreads();
    float acc = bp[e];
    #pragma unroll 8
    for (int f = 0; f < HID; ++f)
        acc = fmaf(s_p[f] * inv, Wp[f * EMB + e], acc);
    out[gi * EMB + e] = acc;
}

// ---------- launcher ----------

extern "C" void kernel_launch(void* const* d_in, const int* in_sizes, int n_in,
                              void* d_out, int out_size, void* d_ws, size_t ws_size,
                              hipStream_t stream) {
    const float* x   = (const float*)d_in[0];
    const int*   src = (const int*)d_in[1];
    const int*   dst = (const int*)d_in[2];
    const int* batch = (const int*)d_in[3];
    const float* W1 = (const float*)d_in[4];
    const float* b1 = (const float*)d_in[5];
    const float* W2 = (const float*)d_in[6];
    const float* b2 = (const float*)d_in[7];
    const float* W3 = (const float*)d_in[8];
    const float* b3 = (const float*)d_in[9];
    const float* g1 = (const float*)d_in[10];
    const float* be1 = (const float*)d_in[11];
    const float* g2 = (const float*)d_in[12];
    const float* be2 = (const float*)d_in[13];
    const float* g3 = (const float*)d_in[14];
    const float* be3 = (const float*)d_in[15];
    const float* Wp = (const float*)d_in[16];
    const float* bp = (const float*)d_in[17];
    float* out = (float*)d_out;

    char* ws = (char*)d_ws;
    size_t o = 0;
    auto alloc = [&](size_t bytes) {
        void* pp = ws + o;
        o += bytes;
        o = (o + 255) & ~255ull;
        return pp;
    };
    int*      cnt       = (int*)alloc(N_NODES * 4);
    int*      fill      = (int*)alloc(N_NODES * 4);
    int*      row_start = (int*)alloc((N_NODES + 1) * 4);
    float*    dinv      = (float*)alloc(N_NODES * 4);
    int2*     e_pack    = (int2*)alloc((size_t)N_EDGES * 8);
    _Float16* Wt2       = (_Float16*)alloc(HID * HID * 2);
    _Float16* Wt3       = (_Float16*)alloc(HID * HID * 2);
    __half2*  H16       = (__half2*)alloc((size_t)(N_NODES + 64) * HID * 2);
    __half2*  H16b      = (__half2*)alloc((size_t)(N_NODES + 64) * HID * 2);
    float*    psum_rep  = (float*)alloc((size_t)NREP * N_GRAPHS * HID * 4);

    hipMemsetAsync(cnt, 0, N_NODES * 4, stream);
    k_count<<<(N_EDGES + 255) / 256, 256, 0, stream>>>(dst, cnt);
    k_scan2<<<NCHUNK, 256, 0, stream>>>(cnt, row_start, dinv, fill, psum_rep,
                                        W2, W3, Wt2, Wt3);
    k_scatter<<<(N_EDGES + 255) / 256, 256, 0, stream>>>(src, dst, dinv, row_start,
                                                         fill, e_pack);
    k_agg5g1<<<(N_NODES * 8 + 255) / 256, 256, 0, stream>>>(x, dinv, row_start, e_pack,
                                                            W1, b1, g1, be1, H16);
    // layer 2: gather H16 -> MFMA(W2) -> H16b
    k_fuse<false><<<(N_NODES + 63) / 64, 256, 0, stream>>>(
        H16, dinv, row_start, e_pack, Wt2, b2, g2, be2,
        (_Float16*)H16b, nullptr, nullptr);
    // layer 3: gather H16b -> MFMA(W3) -> pooled psum_rep
    k_fuse<true><<<(N_NODES + 63) / 64, 256, 0, stream>>>(
        H16b, dinv, row_start, e_pack, Wt3, b3, g3, be3,
        nullptr, batch, psum_rep);
    k_final<<<N_GRAPHS, EMB, 0, stream>>>(psum_rep, batch, Wp, bp, out);
}

// Round 12
// 314.108 us; speedup vs baseline: 1.0623x; 1.0623x over previous
//
#include <hip/hip_runtime.h>
#include <hip/hip_fp16.h>

#define N_NODES 50000
#define N_EDGES 600000
#define N_GRAPHS 64
#define IN_D 5
#define HID 128
#define EMB 64

#define CHUNK 512
#define NCHUNK ((N_NODES + CHUNK - 1) / CHUNK)   // 98
#define NREP 16          // psum replication factor (contention spread)
#define NLOC 4           // per-block local graph slots (64 sorted nodes span <=2-3)

typedef _Float16 half8 __attribute__((ext_vector_type(8)));
typedef float float4v __attribute__((ext_vector_type(4)));

// ---------- 1. degree count (edge atomics; 50k addresses = low contention) ----------

__global__ __launch_bounds__(256) void k_count(
        const int* __restrict__ dst, int* __restrict__ cnt) {
    int e = blockIdx.x * blockDim.x + threadIdx.x;
    if (e < N_EDGES) atomicAdd(&cnt[dst[e]], 1);
}

// ---------- 2. merged CSR scan + dinv + all remaining init (R11, kept) ----------

__global__ __launch_bounds__(256) void k_scan2(
        const int* __restrict__ cnt, int* __restrict__ row_start,
        float* __restrict__ dinv, int* __restrict__ fill,
        float* __restrict__ psum_rep,
        const float* __restrict__ W2, const float* __restrict__ W3,
        _Float16* __restrict__ Wt2, _Float16* __restrict__ Wt3) {
    __shared__ int sh[256];
    __shared__ int ws[4];
    int b = blockIdx.x, t = threadIdx.x;
    int lane = t & 63, w = t >> 6;
    int base = b * CHUNK;

    // chunk prefix: block-reduce cnt[0..base)
    int part = 0;
    for (int j = t; j < base; j += 256) part += cnt[j];
    sh[t] = part; __syncthreads();
    for (int off = 128; off > 0; off >>= 1) {
        if (t < off) sh[t] += sh[t + off];
        __syncthreads();
    }
    int pre = sh[0];

    // local exclusive scan (2 elems/thread)
    int i0 = base + 2 * t, i1 = i0 + 1;
    int c0 = (i0 < N_NODES) ? cnt[i0] : 0;
    int c1 = (i1 < N_NODES) ? cnt[i1] : 0;
    int v = c0 + c1;
    int s = v;
    #pragma unroll
    for (int off = 1; off < 64; off <<= 1) {
        int u = __shfl_up(s, off);
        if (lane >= off) s += u;
    }
    if (lane == 63) ws[w] = s;
    __syncthreads();
    if (t == 0) {
        int r = 0;
        #pragma unroll
        for (int j = 0; j < 4; ++j) { int xx = ws[j]; ws[j] = r; r += xx; }
    }
    __syncthreads();
    int excl = s - v + ws[w] + pre;
    if (i0 < N_NODES) { row_start[i0] = excl;      dinv[i0] = rsqrtf((float)c0 + 1.0f); }
    if (i1 < N_NODES) { row_start[i1] = excl + c0; dinv[i1] = rsqrtf((float)c1 + 1.0f); }
    if (b == 0 && t == 0) row_start[N_NODES] = N_EDGES;

    // absorbed init work (grid-stride over the 98*256 threads)
    int gt = b * 256 + t;
    const int NT = NCHUNK * 256;
    for (int i = gt; i < N_NODES; i += NT) fill[i] = 0;
    for (int i = gt; i < NREP * N_GRAPHS * HID; i += NT) psum_rep[i] = 0.f;
    for (int i = gt; i < 2 * HID * HID; i += NT) {
        int rem = i & (HID * HID - 1);
        int k = rem & 127, f = rem >> 7;
        if (i < HID * HID) Wt2[rem] = (_Float16)W2[k * HID + f];
        else               Wt3[rem] = (_Float16)W3[k * HID + f];
    }
}

// ---------- 3. scatter edges into CSR order ----------

__global__ __launch_bounds__(256) void k_scatter(
        const int* __restrict__ src, const int* __restrict__ dst,
        const float* __restrict__ dinv, const int* __restrict__ row_start,
        int* __restrict__ fill, int2* __restrict__ e_pack) {
    int e = blockIdx.x * blockDim.x + threadIdx.x;
    if (e >= N_EDGES) return;
    int d = dst[e];
    int pos = row_start[d] + atomicAdd(&fill[d], 1);
    int s = src[e];
    e_pack[pos] = make_int2(s, __float_as_int(dinv[s]));
}

// ---------- 4. fused layer 1: agg(x) + gemm1 + bn + relu -> H16 ----------

__global__ __launch_bounds__(256) void k_agg5g1(
        const float* __restrict__ x, const float* __restrict__ dinv,
        const int* __restrict__ row_start, const int2* __restrict__ e_pack,
        const float* __restrict__ W1, const float* __restrict__ b1,
        const float* __restrict__ g1, const float* __restrict__ be1,
        __half2* __restrict__ H16) {
    int gid = blockIdx.x * blockDim.x + threadIdx.x;
    int i = gid >> 3, k = gid & 7;
    if (i >= N_NODES) return;
    float acc = 0.f;
    if (k < IN_D) {
        int beg = row_start[i], end = row_start[i + 1];
        int e = beg;
        for (; e + 3 < end; e += 4) {
            int2 p0 = e_pack[e];
            int2 p1 = e_pack[e + 1];
            int2 p2 = e_pack[e + 2];
            int2 p3 = e_pack[e + 3];
            float x0 = x[p0.x * IN_D + k];
            float x1 = x[p1.x * IN_D + k];
            float x2 = x[p2.x * IN_D + k];
            float x3 = x[p3.x * IN_D + k];
            acc = fmaf(__int_as_float(p0.y), x0, acc);
            acc = fmaf(__int_as_float(p1.y), x1, acc);
            acc = fmaf(__int_as_float(p2.y), x2, acc);
            acc = fmaf(__int_as_float(p3.y), x3, acc);
        }
        for (; e < end; ++e) {
            int2 p = e_pack[e];
            acc = fmaf(__int_as_float(p.y), x[p.x * IN_D + k], acc);
        }
        float di = dinv[i];
        acc = di * (acc + di * x[i * IN_D + k]);
    }
    int lane = threadIdx.x & 63;
    int base = lane & ~7;
    float a0 = __shfl(acc, base + 0);
    float a1 = __shfl(acc, base + 1);
    float a2 = __shfl(acc, base + 2);
    float a3 = __shfl(acc, base + 3);
    float a4 = __shfl(acc, base + 4);
    const float rs = rsqrtf(1.0f + 1e-5f);
    int f0 = k * 16;
    #pragma unroll
    for (int u = 0; u < 8; ++u) {
        int fa = f0 + u * 2, fb = fa + 1;
        float va = b1[fa], vb = b1[fb];
        va = fmaf(a0, W1[0 * HID + fa], va); vb = fmaf(a0, W1[0 * HID + fb], vb);
        va = fmaf(a1, W1[1 * HID + fa], va); vb = fmaf(a1, W1[1 * HID + fb], vb);
        va = fmaf(a2, W1[2 * HID + fa], va); vb = fmaf(a2, W1[2 * HID + fb], vb);
        va = fmaf(a3, W1[3 * HID + fa], va); vb = fmaf(a3, W1[3 * HID + fb], vb);
        va = fmaf(a4, W1[4 * HID + fa], va); vb = fmaf(a4, W1[4 * HID + fb], vb);
        va = fmaf(va, g1[fa] * rs, be1[fa]);
        vb = fmaf(vb, g1[fb] * rs, be1[fb]);
        va = va > 0.f ? va : 0.f;
        vb = vb > 0.f ? vb : 0.f;
        H16[(size_t)i * 64 + k * 8 + u] = __floats2half2_rn(va, vb);
    }
}

// ---------- 5/7. aggregation over fp16 table -> fp16 A (one wave per node: max TLP) ----------
// R11 lesson: fusing this with the GEMM (16 nodes serial per wave) drops gather
// BW from 3.5 to 1.15 TB/s. Keep one node per wave.

__global__ __launch_bounds__(256) void k_agg128h(
        const __half2* __restrict__ H2, const float* __restrict__ dinv,
        const int* __restrict__ row_start, const int2* __restrict__ e_pack,
        __half2* __restrict__ A16) {
    int n = (blockIdx.x * blockDim.x + threadIdx.x) >> 6;
    int lane = threadIdx.x & 63;
    if (n >= N_NODES) return;
    float2 acc = make_float2(0.f, 0.f);
    int beg = row_start[n], end = row_start[n + 1];
    int e = beg;
    for (; e + 7 < end; e += 8) {
        int2 p[8];
        float2 h[8];
        #pragma unroll
        for (int u = 0; u < 8; ++u) p[u] = e_pack[e + u];
        #pragma unroll
        for (int u = 0; u < 8; ++u)
            h[u] = __half22float2(H2[(size_t)p[u].x * 64 + lane]);
        #pragma unroll
        for (int u = 0; u < 8; ++u) {
            float w = __int_as_float(p[u].y);
            acc.x = fmaf(w, h[u].x, acc.x);
            acc.y = fmaf(w, h[u].y, acc.y);
        }
    }
    for (; e + 3 < end; e += 4) {
        int2 p[4];
        float2 h[4];
        #pragma unroll
        for (int u = 0; u < 4; ++u) p[u] = e_pack[e + u];
        #pragma unroll
        for (int u = 0; u < 4; ++u)
            h[u] = __half22float2(H2[(size_t)p[u].x * 64 + lane]);
        #pragma unroll
        for (int u = 0; u < 4; ++u) {
            float w = __int_as_float(p[u].y);
            acc.x = fmaf(w, h[u].x, acc.x);
            acc.y = fmaf(w, h[u].y, acc.y);
        }
    }
    for (; e < end; ++e) {
        int2 pe = e_pack[e];
        float w = __int_as_float(pe.y);
        float2 f = __half22float2(H2[(size_t)pe.x * 64 + lane]);
        acc.x = fmaf(w, f.x, acc.x);
        acc.y = fmaf(w, f.y, acc.y);
    }
    float di = dinv[n];
    float2 hs = __half22float2(H2[(size_t)n * 64 + lane]);
    acc.x = fmaf(di, hs.x, acc.x);
    acc.y = fmaf(di, hs.y, acc.y);
    A16[(size_t)n * 64 + lane] = __floats2half2_rn(di * acc.x, di * acc.y);
}

// ---------- 6. layer-2 MFMA gemm -> H16 (fp16) ----------
// A[m=lane&15][k=quad*8+j]; B via f-major Wt; C/D col=lane&15,row=quad*4+reg.

__global__ __launch_bounds__(256) void k_gemm2(
        const _Float16* __restrict__ A16, const _Float16* __restrict__ Wt,
        const float* __restrict__ bb, const float* __restrict__ gg,
        const float* __restrict__ bee, _Float16* __restrict__ outH) {
    int t = threadIdx.x;
    int w = t >> 6, lane = t & 63;
    int quad = lane >> 4, r16 = lane & 15;
    int nb = blockIdx.x * 64 + w * 16;
    const float rs = rsqrtf(1.0f + 1e-5f);
    const half8* Arow = (const half8*)(A16 + (size_t)(nb + r16) * 128);
    half8 a[4];
    #pragma unroll
    for (int kb = 0; kb < 4; ++kb) a[kb] = Arow[kb * 4 + quad];
    #pragma unroll
    for (int ft = 0; ft < 8; ++ft) {
        int f = ft * 16 + r16;
        const half8* Brow = (const half8*)(Wt + (size_t)f * 128);
        float4v acc = {0.f, 0.f, 0.f, 0.f};
        #pragma unroll
        for (int kb = 0; kb < 4; ++kb)
            acc = __builtin_amdgcn_mfma_f32_16x16x32_f16(a[kb], Brow[kb * 4 + quad],
                                                         acc, 0, 0, 0);
        float b0 = bb[f], g0 = gg[f] * rs, e0 = bee[f];
        #pragma unroll
        for (int rr = 0; rr < 4; ++rr) {
            int n = nb + quad * 4 + rr;
            if (n < N_NODES) {
                float v = fmaf(acc[rr] + b0, g0, e0);
                v = v > 0.f ? v : 0.f;
                outH[(size_t)n * 128 + f] = (_Float16)v;
            }
        }
    }
}

// ---------- 8. layer-3 MFMA gemm + fused mean-pool (LDS + replicated atomics) ----------

__global__ __launch_bounds__(256) void k_gemm3pool(
        const _Float16* __restrict__ A16, const _Float16* __restrict__ Wt,
        const float* __restrict__ bb, const float* __restrict__ gg,
        const float* __restrict__ bee, const int* __restrict__ batch,
        float* __restrict__ psum_rep) {
    __shared__ float sh_pool[NLOC][HID];
    int t = threadIdx.x;
    int w = t >> 6, lane = t & 63;
    int quad = lane >> 4, r16 = lane & 15;
    int blk = (int)blockIdx.x;
    int nb = blk * 64 + w * 16;
    const float rs = rsqrtf(1.0f + 1e-5f);

    for (int i = t; i < NLOC * HID; i += 256) ((float*)sh_pool)[i] = 0.f;

    const half8* Arow = (const half8*)(A16 + (size_t)(nb + r16) * 128);
    half8 a[4];
    #pragma unroll
    for (int kb = 0; kb < 4; ++kb) a[kb] = Arow[kb * 4 + quad];

    int nb0 = blk * 64;
    if (nb0 > N_NODES - 1) nb0 = N_NODES - 1;
    int g0 = batch[nb0];   // first graph id in this 64-node tile
    int gi4[4];
    #pragma unroll
    for (int rr = 0; rr < 4; ++rr) {
        int n = nb + quad * 4 + rr;
        gi4[rr] = (n < N_NODES) ? batch[n] : -1;
    }
    __syncthreads();

    float* rep = psum_rep + (size_t)(blk & (NREP - 1)) * N_GRAPHS * HID;

    #pragma unroll
    for (int ft = 0; ft < 8; ++ft) {
        int f = ft * 16 + r16;
        const half8* Brow = (const half8*)(Wt + (size_t)f * 128);
        float4v acc = {0.f, 0.f, 0.f, 0.f};
        #pragma unroll
        for (int kb = 0; kb < 4; ++kb)
            acc = __builtin_amdgcn_mfma_f32_16x16x32_f16(a[kb], Brow[kb * 4 + quad],
                                                         acc, 0, 0, 0);
        float b0 = bb[f], g0f = gg[f] * rs, e0 = bee[f];
        float partial = 0.f;
        int cur = -1;
        #pragma unroll
        for (int rr = 0; rr < 4; ++rr) {
            int gi = gi4[rr];
            if (gi >= 0) {
                float v = fmaf(acc[rr] + b0, g0f, e0);
                v = v > 0.f ? v : 0.f;
                if (gi != cur) {
                    if (cur >= 0) {
                        int idx = cur - g0;
                        if (idx < NLOC) atomicAdd(&sh_pool[idx][f], partial);
                        else            atomicAdd(&rep[cur * HID + f], partial);
                    }
                    partial = 0.f; cur = gi;
                }
                partial += v;
            }
        }
        if (cur >= 0) {
            int idx = cur - g0;
            if (idx < NLOC) atomicAdd(&sh_pool[idx][f], partial);
            else            atomicAdd(&rep[cur * HID + f], partial);
        }
    }
    __syncthreads();
    for (int i = t; i < NLOC * HID; i += 256) {
        int idx = i >> 7, f = i & 127;
        float v = sh_pool[idx][f];
        int g = g0 + idx;
        if (v != 0.f && g < N_GRAPHS) atomicAdd(&rep[g * HID + f], v);
    }
}

// ---------- 9. projection (+ graph counts via binary search, no atomics) ----------

__device__ __forceinline__ int lower_bound_batch(const int* __restrict__ batch, int val) {
    int lo = 0, hi = N_NODES;
    while (lo < hi) {
        int mid = (lo + hi) >> 1;
        if (batch[mid] < val) lo = mid + 1;
        else hi = mid;
    }
    return lo;
}

__global__ void k_final(const float* __restrict__ psum_rep, const int* __restrict__ batch,
                        const float* __restrict__ Wp, const float* __restrict__ bp,
                        float* __restrict__ out) {
    __shared__ float s_p[HID];
    int gi = blockIdx.x, e = threadIdx.x;   // 64 threads
    for (int f = e; f < HID; f += EMB) {
        float v = 0.f;
        #pragma unroll
        for (int r = 0; r < NREP; ++r)
            v += psum_rep[(size_t)r * N_GRAPHS * HID + gi * HID + f];
        s_p[f] = v;
    }
    int lane = e & 63;
    int r = 0;
    if (lane < 2) r = lower_bound_batch(batch, gi + lane);
    int c0 = __shfl(r, 0), c1 = __shfl(r, 1);
    float inv = 1.0f / fmaxf((float)(c1 - c0), 1.0f);
    __syncthreads();
    float acc = bp[e];
    #pragma unroll 8
    for (int f = 0; f < HID; ++f)
        acc = fmaf(s_p[f] * inv, Wp[f * EMB + e], acc);
    out[gi * EMB + e] = acc;
}

// ---------- launcher ----------

extern "C" void kernel_launch(void* const* d_in, const int* in_sizes, int n_in,
                              void* d_out, int out_size, void* d_ws, size_t ws_size,
                              hipStream_t stream) {
    const float* x   = (const float*)d_in[0];
    const int*   src = (const int*)d_in[1];
    const int*   dst = (const int*)d_in[2];
    const int* batch = (const int*)d_in[3];
    const float* W1 = (const float*)d_in[4];
    const float* b1 = (const float*)d_in[5];
    const float* W2 = (const float*)d_in[6];
    const float* b2 = (const float*)d_in[7];
    const float* W3 = (const float*)d_in[8];
    const float* b3 = (const float*)d_in[9];
    const float* g1 = (const float*)d_in[10];
    const float* be1 = (const float*)d_in[11];
    const float* g2 = (const float*)d_in[12];
    const float* be2 = (const float*)d_in[13];
    const float* g3 = (const float*)d_in[14];
    const float* be3 = (const float*)d_in[15];
    const float* Wp = (const float*)d_in[16];
    const float* bp = (const float*)d_in[17];
    float* out = (float*)d_out;

    char* ws = (char*)d_ws;
    size_t o = 0;
    auto alloc = [&](size_t bytes) {
        void* pp = ws + o;
        o += bytes;
        o = (o + 255) & ~255ull;
        return pp;
    };
    int*      cnt       = (int*)alloc(N_NODES * 4);
    int*      fill      = (int*)alloc(N_NODES * 4);
    int*      row_start = (int*)alloc((N_NODES + 1) * 4);
    float*    dinv      = (float*)alloc(N_NODES * 4);
    int2*     e_pack    = (int2*)alloc((size_t)N_EDGES * 8);
    _Float16* Wt2       = (_Float16*)alloc(HID * HID * 2);
    _Float16* Wt3       = (_Float16*)alloc(HID * HID * 2);
    __half2*  H16       = (__half2*)alloc((size_t)(N_NODES + 64) * HID * 2);
    __half2*  A16       = (__half2*)alloc((size_t)(N_NODES + 64) * HID * 2);
    float*    psum_rep  = (float*)alloc((size_t)NREP * N_GRAPHS * HID * 4);

    hipMemsetAsync(cnt, 0, N_NODES * 4, stream);
    k_count<<<(N_EDGES + 255) / 256, 256, 0, stream>>>(dst, cnt);
    k_scan2<<<NCHUNK, 256, 0, stream>>>(cnt, row_start, dinv, fill, psum_rep,
                                        W2, W3, Wt2, Wt3);
    k_scatter<<<(N_EDGES + 255) / 256, 256, 0, stream>>>(src, dst, dinv, row_start,
                                                         fill, e_pack);
    k_agg5g1<<<(N_NODES * 8 + 255) / 256, 256, 0, stream>>>(x, dinv, row_start, e_pack,
                                                            W1, b1, g1, be1, H16);
    // layer 2
    k_agg128h<<<(N_NODES * 64 + 255) / 256, 256, 0, stream>>>(H16, dinv, row_start,
                                                              e_pack, A16);
    k_gemm2<<<(N_NODES + 63) / 64, 256, 0, stream>>>((const _Float16*)A16, Wt2,
                                                     b2, g2, be2, (_Float16*)H16);
    // layer 3
    k_agg128h<<<(N_NODES * 64 + 255) / 256, 256, 0, stream>>>(H16, dinv, row_start,
                                                              e_pack, A16);
    k_gemm3pool<<<(N_NODES + 63) / 64, 256, 0, stream>>>((const _Float16*)A16, Wt3,
                                                         b3, g3, be3, batch, psum_rep);
    k_final<<<N_GRAPHS, EMB, 0, stream>>>(psum_rep, batch, Wp, bp, out);
}

// Round 13
// 311.082 us; speedup vs baseline: 1.0726x; 1.0097x over previous
//
#include <hip/hip_runtime.h>
#include <hip/hip_fp16.h>

#define N_NODES 50000
#define N_EDGES 600000
#define N_GRAPHS 64
#define IN_D 5
#define HID 128
#define EMB 64

#define CHUNK 512
#define NCHUNK ((N_NODES + CHUNK - 1) / CHUNK)   // 98
#define NREP 16          // psum replication factor (contention spread)
#define NLOC 4           // per-block local graph slots
#define RSTR 136         // LDS row stride in halves (272B): 16B-aligned frags, conflict-free writes

typedef _Float16 half8 __attribute__((ext_vector_type(8)));
typedef _Float16 half2v __attribute__((ext_vector_type(2)));
typedef float float4v __attribute__((ext_vector_type(4)));

// ---------- 1. degree count ----------

__global__ __launch_bounds__(256) void k_count(
        const int* __restrict__ dst, int* __restrict__ cnt) {
    int e = blockIdx.x * blockDim.x + threadIdx.x;
    if (e < N_EDGES) atomicAdd(&cnt[dst[e]], 1);
}

// ---------- 2. merged CSR scan + dinv + init + Wt transpose ----------

__global__ __launch_bounds__(256) void k_scan2(
        const int* __restrict__ cnt, int* __restrict__ row_start,
        float* __restrict__ dinv, int* __restrict__ fill,
        float* __restrict__ psum_rep,
        const float* __restrict__ W2, const float* __restrict__ W3,
        _Float16* __restrict__ Wt2, _Float16* __restrict__ Wt3) {
    __shared__ int sh[256];
    __shared__ int ws[4];
    int b = blockIdx.x, t = threadIdx.x;
    int lane = t & 63, w = t >> 6;
    int base = b * CHUNK;

    int part = 0;
    for (int j = t; j < base; j += 256) part += cnt[j];
    sh[t] = part; __syncthreads();
    for (int off = 128; off > 0; off >>= 1) {
        if (t < off) sh[t] += sh[t + off];
        __syncthreads();
    }
    int pre = sh[0];

    int i0 = base + 2 * t, i1 = i0 + 1;
    int c0 = (i0 < N_NODES) ? cnt[i0] : 0;
    int c1 = (i1 < N_NODES) ? cnt[i1] : 0;
    int v = c0 + c1;
    int s = v;
    #pragma unroll
    for (int off = 1; off < 64; off <<= 1) {
        int u = __shfl_up(s, off);
        if (lane >= off) s += u;
    }
    if (lane == 63) ws[w] = s;
    __syncthreads();
    if (t == 0) {
        int r = 0;
        #pragma unroll
        for (int j = 0; j < 4; ++j) { int xx = ws[j]; ws[j] = r; r += xx; }
    }
    __syncthreads();
    int excl = s - v + ws[w] + pre;
    if (i0 < N_NODES) { row_start[i0] = excl;      dinv[i0] = rsqrtf((float)c0 + 1.0f); }
    if (i1 < N_NODES) { row_start[i1] = excl + c0; dinv[i1] = rsqrtf((float)c1 + 1.0f); }
    if (b == 0 && t == 0) row_start[N_NODES] = N_EDGES;

    int gt = b * 256 + t;
    const int NT = NCHUNK * 256;
    for (int i = gt; i < N_NODES; i += NT) fill[i] = 0;
    for (int i = gt; i < NREP * N_GRAPHS * HID; i += NT) psum_rep[i] = 0.f;
    for (int i = gt; i < 2 * HID * HID; i += NT) {
        int rem = i & (HID * HID - 1);
        int k = rem & 127, f = rem >> 7;
        if (i < HID * HID) Wt2[rem] = (_Float16)W2[k * HID + f];
        else               Wt3[rem] = (_Float16)W3[k * HID + f];
    }
}

// ---------- 3. scatter edges into CSR order ----------

__global__ __launch_bounds__(256) void k_scatter(
        const int* __restrict__ src, const int* __restrict__ dst,
        const float* __restrict__ dinv, const int* __restrict__ row_start,
        int* __restrict__ fill, int2* __restrict__ e_pack) {
    int e = blockIdx.x * blockDim.x + threadIdx.x;
    if (e >= N_EDGES) return;
    int d = dst[e];
    int pos = row_start[d] + atomicAdd(&fill[d], 1);
    int s = src[e];
    e_pack[pos] = make_int2(s, __float_as_int(dinv[s]));
}

// ---------- 4. fused layer 1: agg(x) + gemm1 + bn + relu -> H16 ----------

__global__ __launch_bounds__(256) void k_agg5g1(
        const float* __restrict__ x, const float* __restrict__ dinv,
        const int* __restrict__ row_start, const int2* __restrict__ e_pack,
        const float* __restrict__ W1, const float* __restrict__ b1,
        const float* __restrict__ g1, const float* __restrict__ be1,
        __half2* __restrict__ H16) {
    int gid = blockIdx.x * blockDim.x + threadIdx.x;
    int i = gid >> 3, k = gid & 7;
    if (i >= N_NODES) return;
    float acc = 0.f;
    if (k < IN_D) {
        int beg = row_start[i], end = row_start[i + 1];
        int e = beg;
        for (; e + 3 < end; e += 4) {
            int2 p0 = e_pack[e];
            int2 p1 = e_pack[e + 1];
            int2 p2 = e_pack[e + 2];
            int2 p3 = e_pack[e + 3];
            float x0 = x[p0.x * IN_D + k];
            float x1 = x[p1.x * IN_D + k];
            float x2 = x[p2.x * IN_D + k];
            float x3 = x[p3.x * IN_D + k];
            acc = fmaf(__int_as_float(p0.y), x0, acc);
            acc = fmaf(__int_as_float(p1.y), x1, acc);
            acc = fmaf(__int_as_float(p2.y), x2, acc);
            acc = fmaf(__int_as_float(p3.y), x3, acc);
        }
        for (; e < end; ++e) {
            int2 p = e_pack[e];
            acc = fmaf(__int_as_float(p.y), x[p.x * IN_D + k], acc);
        }
        float di = dinv[i];
        acc = di * (acc + di * x[i * IN_D + k]);
    }
    int lane = threadIdx.x & 63;
    int base = lane & ~7;
    float a0 = __shfl(acc, base + 0);
    float a1 = __shfl(acc, base + 1);
    float a2 = __shfl(acc, base + 2);
    float a3 = __shfl(acc, base + 3);
    float a4 = __shfl(acc, base + 4);
    const float rs = rsqrtf(1.0f + 1e-5f);
    int f0 = k * 16;
    #pragma unroll
    for (int u = 0; u < 8; ++u) {
        int fa = f0 + u * 2, fb = fa + 1;
        float va = b1[fa], vb = b1[fb];
        va = fmaf(a0, W1[0 * HID + fa], va); vb = fmaf(a0, W1[0 * HID + fb], vb);
        va = fmaf(a1, W1[1 * HID + fa], va); vb = fmaf(a1, W1[1 * HID + fb], vb);
        va = fmaf(a2, W1[2 * HID + fa], va); vb = fmaf(a2, W1[2 * HID + fb], vb);
        va = fmaf(a3, W1[3 * HID + fa], va); vb = fmaf(a3, W1[3 * HID + fb], vb);
        va = fmaf(a4, W1[4 * HID + fa], va); vb = fmaf(a4, W1[4 * HID + fb], vb);
        va = fmaf(va, g1[fa] * rs, be1[fa]);
        vb = fmaf(vb, g1[fb] * rs, be1[fb]);
        va = va > 0.f ? va : 0.f;
        vb = vb > 0.f ? vb : 0.f;
        H16[(size_t)i * 64 + k * 8 + u] = __floats2half2_rn(va, vb);
    }
}

// ---------- 5/6. fused gather + MFMA layer (1024 threads, 1 wave = 1 node) ----------
// 16 waves each gather ONE node (full TLP, the R11 lesson) into a 16-row LDS
// tile; barrier; waves 0-7 run the 8 MFMA column-tiles. 50000 = 16*3125: no tail.
// A[m=lane&15][k=quad*8+j] from LDS; B via f-major Wt; C/D col=lane&15,row=quad*4+reg.

template <bool POOL>
__global__ __launch_bounds__(1024, 2) void k_aggemm(
        const __half2* __restrict__ Hsrc, const float* __restrict__ dinv,
        const int* __restrict__ row_start, const int2* __restrict__ e_pack,
        const _Float16* __restrict__ Wt, const float* __restrict__ bb,
        const float* __restrict__ gg, const float* __restrict__ bee,
        _Float16* __restrict__ Hdst,
        const int* __restrict__ batch, float* __restrict__ psum_rep) {
    __shared__ _Float16 shA[16 * RSTR];     // 4352 B
    __shared__ float sh_pool[NLOC][HID];    // 2 KB (POOL only)
    int t = threadIdx.x;
    int w = t >> 6, lane = t & 63;
    int blk = (int)blockIdx.x;
    int n = blk * 16 + w;                   // this wave's node
    const float rs = rsqrtf(1.0f + 1e-5f);

    if (POOL) {
        for (int i = t; i < NLOC * HID; i += 1024) ((float*)sh_pool)[i] = 0.f;
    }

    // --- gather: one full wave per node (max MLP/TLP) ---
    float2 acc = make_float2(0.f, 0.f);
    {
        int beg = row_start[n], end = row_start[n + 1];
        int e = beg;
        for (; e + 7 < end; e += 8) {
            int2 p[8];
            float2 h[8];
            #pragma unroll
            for (int u = 0; u < 8; ++u) p[u] = e_pack[e + u];
            #pragma unroll
            for (int u = 0; u < 8; ++u)
                h[u] = __half22float2(Hsrc[(size_t)p[u].x * 64 + lane]);
            #pragma unroll
            for (int u = 0; u < 8; ++u) {
                float wt = __int_as_float(p[u].y);
                acc.x = fmaf(wt, h[u].x, acc.x);
                acc.y = fmaf(wt, h[u].y, acc.y);
            }
        }
        for (; e + 3 < end; e += 4) {
            int2 p[4];
            float2 h[4];
            #pragma unroll
            for (int u = 0; u < 4; ++u) p[u] = e_pack[e + u];
            #pragma unroll
            for (int u = 0; u < 4; ++u)
                h[u] = __half22float2(Hsrc[(size_t)p[u].x * 64 + lane]);
            #pragma unroll
            for (int u = 0; u < 4; ++u) {
                float wt = __int_as_float(p[u].y);
                acc.x = fmaf(wt, h[u].x, acc.x);
                acc.y = fmaf(wt, h[u].y, acc.y);
            }
        }
        for (; e < end; ++e) {
            int2 pe = e_pack[e];
            float wt = __int_as_float(pe.y);
            float2 f = __half22float2(Hsrc[(size_t)pe.x * 64 + lane]);
            acc.x = fmaf(wt, f.x, acc.x);
            acc.y = fmaf(wt, f.y, acc.y);
        }
        float di = dinv[n];
        float2 hs = __half22float2(Hsrc[(size_t)n * 64 + lane]);
        acc.x = di * fmaf(di, hs.x, acc.x);
        acc.y = di * fmaf(di, hs.y, acc.y);
    }
    // LDS write: word = 68*w + lane -> bank (4w+lane)%32, 2 lanes/bank = free
    half2v hv = { (_Float16)acc.x, (_Float16)acc.y };
    *(half2v*)(shA + w * RSTR + lane * 2) = hv;
    __syncthreads();

    // --- MFMA: waves 0-7, wave w computes cols [16w, 16w+16) for all 16 rows ---
    if (w < 8) {
        int quad = lane >> 4, r16 = lane & 15;
        half8 a[4];
        #pragma unroll
        for (int kb = 0; kb < 4; ++kb)
            a[kb] = *(const half8*)(shA + r16 * RSTR + kb * 32 + quad * 8);

        int f = w * 16 + r16;
        const half8* Brow = (const half8*)(Wt + (size_t)f * 128);
        float4v acc4 = {0.f, 0.f, 0.f, 0.f};
        #pragma unroll
        for (int kb = 0; kb < 4; ++kb)
            acc4 = __builtin_amdgcn_mfma_f32_16x16x32_f16(a[kb], Brow[kb * 4 + quad],
                                                          acc4, 0, 0, 0);
        float b0 = bb[f], g0f = gg[f] * rs, e0 = bee[f];

        if (POOL) {
            int g0 = batch[blk * 16];
            float* rep = psum_rep + (size_t)(blk & (NREP - 1)) * N_GRAPHS * HID;
            float partial = 0.f;
            int cur = -1;
            #pragma unroll
            for (int rr = 0; rr < 4; ++rr) {
                int nn = blk * 16 + quad * 4 + rr;
                int gi = batch[nn];
                float v = fmaf(acc4[rr] + b0, g0f, e0);
                v = v > 0.f ? v : 0.f;
                if (gi != cur) {
                    if (cur >= 0) {
                        int idx = cur - g0;
                        if (idx < NLOC) atomicAdd(&sh_pool[idx][f], partial);
                        else            atomicAdd(&rep[cur * HID + f], partial);
                    }
                    partial = 0.f; cur = gi;
                }
                partial += v;
            }
            if (cur >= 0) {
                int idx = cur - g0;
                if (idx < NLOC) atomicAdd(&sh_pool[idx][f], partial);
                else            atomicAdd(&rep[cur * HID + f], partial);
            }
        } else {
            #pragma unroll
            for (int rr = 0; rr < 4; ++rr) {
                int nn = blk * 16 + quad * 4 + rr;
                float v = fmaf(acc4[rr] + b0, g0f, e0);
                v = v > 0.f ? v : 0.f;
                Hdst[(size_t)nn * 128 + f] = (_Float16)v;
            }
        }
    }

    if (POOL) {
        __syncthreads();
        int g0 = batch[blk * 16];
        float* rep = psum_rep + (size_t)(blk & (NREP - 1)) * N_GRAPHS * HID;
        for (int i = t; i < NLOC * HID; i += 1024) {
            int idx = i >> 7, f = i & 127;
            float v = sh_pool[idx][f];
            int g = g0 + idx;
            if (v != 0.f && g < N_GRAPHS) atomicAdd(&rep[g * HID + f], v);
        }
    }
}

// ---------- 7. projection (+ graph counts via binary search) ----------

__device__ __forceinline__ int lower_bound_batch(const int* __restrict__ batch, int val) {
    int lo = 0, hi = N_NODES;
    while (lo < hi) {
        int mid = (lo + hi) >> 1;
        if (batch[mid] < val) lo = mid + 1;
        else hi = mid;
    }
    return lo;
}

__global__ void k_final(const float* __restrict__ psum_rep, const int* __restrict__ batch,
                        const float* __restrict__ Wp, const float* __restrict__ bp,
                        float* __restrict__ out) {
    __shared__ float s_p[HID];
    int gi = blockIdx.x, e = threadIdx.x;   // 64 threads
    for (int f = e; f < HID; f += EMB) {
        float v = 0.f;
        #pragma unroll
        for (int r = 0; r < NREP; ++r)
            v += psum_rep[(size_t)r * N_GRAPHS * HID + gi * HID + f];
        s_p[f] = v;
    }
    int lane = e & 63;
    int r = 0;
    if (lane < 2) r = lower_bound_batch(batch, gi + lane);
    int c0 = __shfl(r, 0), c1 = __shfl(r, 1);
    float inv = 1.0f / fmaxf((float)(c1 - c0), 1.0f);
    __syncthreads();
    float acc = bp[e];
    #pragma unroll 8
    for (int f = 0; f < HID; ++f)
        acc = fmaf(s_p[f] * inv, Wp[f * EMB + e], acc);
    out[gi * EMB + e] = acc;
}

// ---------- launcher ----------

extern "C" void kernel_launch(void* const* d_in, const int* in_sizes, int n_in,
                              void* d_out, int out_size, void* d_ws, size_t ws_size,
                              hipStream_t stream) {
    const float* x   = (const float*)d_in[0];
    const int*   src = (const int*)d_in[1];
    const int*   dst = (const int*)d_in[2];
    const int* batch = (const int*)d_in[3];
    const float* W1 = (const float*)d_in[4];
    const float* b1 = (const float*)d_in[5];
    const float* W2 = (const float*)d_in[6];
    const float* b2 = (const float*)d_in[7];
    const float* W3 = (const float*)d_in[8];
    const float* b3 = (const float*)d_in[9];
    const float* g1 = (const float*)d_in[10];
    const float* be1 = (const float*)d_in[11];
    const float* g2 = (const float*)d_in[12];
    const float* be2 = (const float*)d_in[13];
    const float* g3 = (const float*)d_in[14];
    const float* be3 = (const float*)d_in[15];
    const float* Wp = (const float*)d_in[16];
    const float* bp = (const float*)d_in[17];
    float* out = (float*)d_out;

    char* ws = (char*)d_ws;
    size_t o = 0;
    auto alloc = [&](size_t bytes) {
        void* pp = ws + o;
        o += bytes;
        o = (o + 255) & ~255ull;
        return pp;
    };
    int*      cnt       = (int*)alloc(N_NODES * 4);
    int*      fill      = (int*)alloc(N_NODES * 4);
    int*      row_start = (int*)alloc((N_NODES + 1) * 4);
    float*    dinv      = (float*)alloc(N_NODES * 4);
    int2*     e_pack    = (int2*)alloc((size_t)N_EDGES * 8);
    _Float16* Wt2       = (_Float16*)alloc(HID * HID * 2);
    _Float16* Wt3       = (_Float16*)alloc(HID * HID * 2);
    __half2*  H16       = (__half2*)alloc((size_t)N_NODES * HID * 2);
    __half2*  H16b      = (__half2*)alloc((size_t)N_NODES * HID * 2);
    float*    psum_rep  = (float*)alloc((size_t)NREP * N_GRAPHS * HID * 4);

    hipMemsetAsync(cnt, 0, N_NODES * 4, stream);
    k_count<<<(N_EDGES + 255) / 256, 256, 0, stream>>>(dst, cnt);
    k_scan2<<<NCHUNK, 256, 0, stream>>>(cnt, row_start, dinv, fill, psum_rep,
                                        W2, W3, Wt2, Wt3);
    k_scatter<<<(N_EDGES + 255) / 256, 256, 0, stream>>>(src, dst, dinv, row_start,
                                                         fill, e_pack);
    k_agg5g1<<<(N_NODES * 8 + 255) / 256, 256, 0, stream>>>(x, dinv, row_start, e_pack,
                                                            W1, b1, g1, be1, H16);
    // layer 2: gather H16 -> LDS -> MFMA(W2) -> H16b   (3125 blocks, 16 nodes each)
    k_aggemm<false><<<N_NODES / 16, 1024, 0, stream>>>(
        H16, dinv, row_start, e_pack, Wt2, b2, g2, be2,
        (_Float16*)H16b, nullptr, nullptr);
    // layer 3: gather H16b -> LDS -> MFMA(W3) -> pooled psum_rep
    k_aggemm<true><<<N_NODES / 16, 1024, 0, stream>>>(
        H16b, dinv, row_start, e_pack, Wt3, b3, g3, be3,
        nullptr, batch, psum_rep);
    k_final<<<N_GRAPHS, EMB, 0, stream>>>(psum_rep, batch, Wp, bp, out);
}